// Round 1
// baseline (438.093 us; speedup 1.0000x reference)
//
#include <hip/hip_runtime.h>
#include <hip/hip_bf16.h>

// Reverse cummax along axis 1 of a [B=16, H=128, W=128, C=256] fp32 tensor.
// out[b,h,w,c] = max_{h'>=h} in[b,h',w,c].
// One thread per (b, w, c/4) column; float4 loads/stores; walk h backwards.

#define B 16
#define H 128
#define W 128
#define C4 64   // C/4 = 256/4

__global__ void __launch_bounds__(256) rev_cummax_kernel(
    const float4* __restrict__ in, float4* __restrict__ out) {
    int tid = blockIdx.x * blockDim.x + threadIdx.x;  // 0 .. B*W*C4-1
    // decompose: c4 = tid & 63, w = (tid >> 6) & 127, b = tid >> 13
    int c4 = tid & (C4 - 1);
    int w  = (tid >> 6) & (W - 1);
    int b  = tid >> 13;

    const int hstride = W * C4;  // float4 elements per h step (8192)
    // start at h = H-1
    int idx = ((b * H + (H - 1)) * W + w) * C4 + c4;

    float4 m = in[idx];
    out[idx] = m;
    idx -= hstride;

#pragma unroll 4
    for (int h = H - 2; h >= 0; --h) {
        float4 v = in[idx];
        m.x = fmaxf(m.x, v.x);
        m.y = fmaxf(m.y, v.y);
        m.z = fmaxf(m.z, v.z);
        m.w = fmaxf(m.w, v.w);
        out[idx] = m;
        idx -= hstride;
    }
}

extern "C" void kernel_launch(void* const* d_in, const int* in_sizes, int n_in,
                              void* d_out, int out_size, void* d_ws, size_t ws_size,
                              hipStream_t stream) {
    const float4* in = (const float4*)d_in[0];
    float4* out = (float4*)d_out;
    const int nthreads = B * W * C4;  // 131072
    rev_cummax_kernel<<<nthreads / 256, 256, 0, stream>>>(in, out);
}